// Round 1
// baseline (1243.585 us; speedup 1.0000x reference)
//
#include <hip/hip_runtime.h>
#include <cstdint>
#include <cstddef>

#define B_N 2048
#define M_N 768
#define E_N 16384
#define K_N 32
#define EPSF 1e-8f

// ---------------------------------------------------------------------------
// Column stats of the three decoders: np2, n1, n2, dp1, dp2  (each length E)
// out5 layout: [np2 | n1 | n2 | dp1 | dp2]
// ---------------------------------------------------------------------------
__global__ void colstats_kernel(const float* __restrict__ dw, const float* __restrict__ d1,
                                const float* __restrict__ d2, float* __restrict__ out5) {
  int e = blockIdx.x * 256 + threadIdx.x;
  float s0 = 0.f, s1 = 0.f, s2 = 0.f, s3 = 0.f, s4 = 0.f;
  for (int m = 0; m < M_N; ++m) {
    float a  = dw[(size_t)m * E_N + e];
    float b1 = d1[(size_t)m * E_N + e];
    float b2 = d2[(size_t)m * E_N + e];
    s0 = fmaf(a, a, s0);
    s1 = fmaf(b1, b1, s1);
    s2 = fmaf(b2, b2, s2);
    s3 = fmaf(a, b1, s3);
    s4 = fmaf(a, b2, s4);
  }
  out5[e] = s0;
  out5[E_N + e] = s1;
  out5[2 * E_N + e] = s2;
  out5[3 * E_N + e] = s3;
  out5[4 * E_N + e] = s4;
}

// ---------------------------------------------------------------------------
// Transpose [M_N, E_N] -> [E_N, M_N] (32x32 LDS tiles)
// ---------------------------------------------------------------------------
__global__ void transpose_kernel(const float* __restrict__ in, float* __restrict__ out) {
  __shared__ float tile[32][33];
  int tx = threadIdx.x;  // 32
  int ty = threadIdx.y;  // 8
  int e = blockIdx.x * 32 + tx;
  for (int r = 0; r < 32; r += 8) {
    int m = blockIdx.y * 32 + ty + r;
    tile[ty + r][tx] = in[(size_t)m * E_N + e];
  }
  __syncthreads();
  int m2 = blockIdx.y * 32 + tx;
  for (int r = 0; r < 32; r += 8) {
    int e2 = blockIdx.x * 32 + ty + r;
    out[(size_t)e2 * M_N + m2] = tile[tx][ty + r];
  }
}

// ---------------------------------------------------------------------------
// pre = x @ enc_w.T + enc_b   (f32 vector-ALU tiled GEMM, NT layout)
// A = x [B_N, 768], Bm = enc_w [E_N, 768], C = pre [B_N, E_N]
// 128x128 tile, BK=32, 256 threads, 8x8 per thread.
// ---------------------------------------------------------------------------
#define GBM 128
#define GBN 128
#define GBK 32
#define LSTR 132  // padded LDS row stride (k-major), breaks store conflicts

__global__ __launch_bounds__(256) void gemm_pre_kernel(const float* __restrict__ A,
                                                       const float* __restrict__ Bm,
                                                       const float* __restrict__ bias,
                                                       float* __restrict__ C) {
  __shared__ float As[GBK * LSTR];
  __shared__ float Bs[GBK * LSTR];
  int tid = threadIdx.x;
  int tx = tid & 15;   // col group
  int ty = tid >> 4;   // row group
  int i0 = blockIdx.y * GBM;
  int j0 = blockIdx.x * GBN;

  float acc[8][8];
#pragma unroll
  for (int i = 0; i < 8; ++i)
#pragma unroll
    for (int j = 0; j < 8; ++j) acc[i][j] = 0.f;

  for (int k0 = 0; k0 < M_N; k0 += GBK) {
#pragma unroll
    for (int p = 0; p < 4; ++p) {
      int q = tid + p * 256;       // 0..1023
      int k4 = q & 7;              // float4 index along k (8 per row)
      int row = q >> 3;            // 0..127
      float4 va = *(const float4*)&A[(size_t)(i0 + row) * M_N + k0 + (k4 << 2)];
      float4 vb = *(const float4*)&Bm[(size_t)(j0 + row) * M_N + k0 + (k4 << 2)];
      int kk = k4 << 2;
      As[(kk + 0) * LSTR + row] = va.x;
      As[(kk + 1) * LSTR + row] = va.y;
      As[(kk + 2) * LSTR + row] = va.z;
      As[(kk + 3) * LSTR + row] = va.w;
      Bs[(kk + 0) * LSTR + row] = vb.x;
      Bs[(kk + 1) * LSTR + row] = vb.y;
      Bs[(kk + 2) * LSTR + row] = vb.z;
      Bs[(kk + 3) * LSTR + row] = vb.w;
    }
    __syncthreads();

#pragma unroll 8
    for (int k = 0; k < GBK; ++k) {
      float4 a0 = *(const float4*)&As[k * LSTR + (ty << 2)];
      float4 a1 = *(const float4*)&As[k * LSTR + (ty << 2) + 64];
      float4 b0 = *(const float4*)&Bs[k * LSTR + (tx << 2)];
      float4 b1 = *(const float4*)&Bs[k * LSTR + (tx << 2) + 64];
      float av[8] = {a0.x, a0.y, a0.z, a0.w, a1.x, a1.y, a1.z, a1.w};
      float bv[8] = {b0.x, b0.y, b0.z, b0.w, b1.x, b1.y, b1.z, b1.w};
#pragma unroll
      for (int ii = 0; ii < 8; ++ii)
#pragma unroll
        for (int jj = 0; jj < 8; ++jj) acc[ii][jj] = fmaf(av[ii], bv[jj], acc[ii][jj]);
    }
    __syncthreads();
  }

  float4 bb0 = *(const float4*)&bias[j0 + (tx << 2)];
  float4 bb1 = *(const float4*)&bias[j0 + (tx << 2) + 64];
#pragma unroll
  for (int ii = 0; ii < 8; ++ii) {
    int row = i0 + (ty << 2) + (ii < 4 ? ii : 60 + ii);  // ii>=4 -> 64+(ii-4)
    float4 o0 = make_float4(acc[ii][0] + bb0.x, acc[ii][1] + bb0.y,
                            acc[ii][2] + bb0.z, acc[ii][3] + bb0.w);
    float4 o1 = make_float4(acc[ii][4] + bb1.x, acc[ii][5] + bb1.y,
                            acc[ii][6] + bb1.z, acc[ii][7] + bb1.w);
    *(float4*)&C[(size_t)row * E_N + j0 + (tx << 2)] = o0;
    *(float4*)&C[(size_t)row * E_N + j0 + (tx << 2) + 64] = o1;
  }
}

// ---------------------------------------------------------------------------
// Top-K per row via per-thread cached max + winner rescan. Destroys `pre`.
// ---------------------------------------------------------------------------
__global__ __launch_bounds__(256) void topk_kernel(float* __restrict__ pre,
                                                   int* __restrict__ topk_idx,
                                                   float* __restrict__ topk_val,
                                                   int* __restrict__ live_p) {
  int b = blockIdx.x;
  int tid = threadIdx.x;
  float* row = pre + (size_t)b * E_N;

  __shared__ float rv[256];
  __shared__ int ri[256];
  __shared__ float wv_s;
  __shared__ int wi_s, wt_s;

  float best = -INFINITY;
  int bidx = 0x7fffffff;
  for (int j = 0; j < E_N / 256; ++j) {
    int i = tid + j * 256;
    float v = row[i];
    if (v > best) { best = v; bidx = i; }
  }
  rv[tid] = best;
  ri[tid] = bidx;
  __syncthreads();

  for (int iter = 0; iter < K_N; ++iter) {
    if (tid < 64) {
      float v = rv[tid];
      int idx = ri[tid];
      int owner = tid;
#pragma unroll
      for (int s = 64; s < 256; s += 64) {
        float v2 = rv[tid + s];
        int i2 = ri[tid + s];
        if (v2 > v || (v2 == v && i2 < idx)) { v = v2; idx = i2; owner = tid + s; }
      }
#pragma unroll
      for (int off = 32; off > 0; off >>= 1) {
        float v2 = __shfl_down(v, off);
        int i2 = __shfl_down(idx, off);
        int o2 = __shfl_down(owner, off);
        if (v2 > v || (v2 == v && i2 < idx)) { v = v2; idx = i2; owner = o2; }
      }
      if (tid == 0) { wv_s = v; wi_s = idx; wt_s = owner; }
    }
    __syncthreads();
    int widx = wi_s;
    int wtid = wt_s;
    if (tid == 0) {
      topk_idx[b * K_N + iter] = widx;
      topk_val[b * K_N + iter] = wv_s;
      live_p[widx] = 1;
    }
    if (tid == wtid) {
      row[widx] = -INFINITY;
      float nb = -INFINITY;
      int nbi = 0x7fffffff;
      for (int j = 0; j < E_N / 256; ++j) {
        int i = tid + j * 256;
        float v2 = row[i];
        if (v2 > nb) { nb = v2; nbi = i; }
      }
      rv[tid] = nb;
      ri[tid] = nbi;
    }
    __syncthreads();
  }
}

// ---------------------------------------------------------------------------
// Per-active-slot children: pre1/pre2 dots, winner, c value, liveness, aux.
// stats layout: [np2 | n1 | n2 | dp1 | dp2]
// ---------------------------------------------------------------------------
__global__ __launch_bounds__(256) void child_kernel(
    const float* __restrict__ x, const float* __restrict__ e1w, const float* __restrict__ e1b,
    const float* __restrict__ e2w, const float* __restrict__ e2b,
    const int* __restrict__ topk_idx, const float* __restrict__ topk_val,
    float* __restrict__ child_c, int* __restrict__ win_flag,
    int* __restrict__ live_c1, int* __restrict__ live_c2,
    const float* __restrict__ stats, float* __restrict__ aux_sum) {
  int b = blockIdx.x;
  int tid = threadIdx.x;
  int lane = tid & 63;
  int wave = tid >> 6;

  __shared__ float xs[M_N];
  __shared__ float wsum[4];
  for (int i = tid; i < M_N; i += 256) xs[i] = x[(size_t)b * M_N + i];
  __syncthreads();

  float cos_acc = 0.f;
  for (int s = wave; s < K_N; s += 4) {
    int e = topk_idx[b * K_N + s];
    float a = topk_val[b * K_N + s];
    if (a != 0.f) {
      float d1 = 0.f, d2 = 0.f;
#pragma unroll
      for (int j = 0; j < 3; ++j) {
        int m = (lane << 2) + j * 256;
        float4 xv = *(const float4*)&xs[m];
        float4 w1 = *(const float4*)&e1w[(size_t)e * M_N + m];
        float4 w2 = *(const float4*)&e2w[(size_t)e * M_N + m];
        d1 += xv.x * w1.x + xv.y * w1.y + xv.z * w1.z + xv.w * w1.w;
        d2 += xv.x * w2.x + xv.y * w2.y + xv.z * w2.z + xv.w * w2.w;
      }
#pragma unroll
      for (int off = 32; off > 0; off >>= 1) {
        d1 += __shfl_down(d1, off);
        d2 += __shfl_down(d2, off);
      }
      if (lane == 0) {
        float m1 = d1 + e1b[e];
        float m2 = d2 + e2b[e];
        bool win = m1 > m2;
        float f1 = win ? m1 : 0.f;
        float f2 = win ? 0.f : m2;
        float c = win ? f1 : f2;
        child_c[b * K_N + s] = c;
        win_flag[b * K_N + s] = win ? 1 : 0;
        if (f1 != 0.f) live_c1[e] = 1;
        if (f2 != 0.f) live_c2[e] = 1;
        if (a > 0.f) {
          float np2e = stats[e];
          float nce = win ? stats[E_N + e] : stats[2 * E_N + e];
          float dpc = win ? stats[3 * E_N + e] : stats[4 * E_N + e];
          float a2 = a * a;
          float dot = a2 * np2e + a * c * dpc;
          float normp = fabsf(a) * sqrtf(np2e);
          float comb2 = a2 * np2e + 2.f * a * c * dpc + c * c * nce;
          float normc = sqrtf(fmaxf(comb2, 0.f));
          cos_acc += dot / (fmaxf(normp, EPSF) * fmaxf(normc, EPSF));
        }
      }
    } else if (lane == 0) {
      child_c[b * K_N + s] = 0.f;
      win_flag[b * K_N + s] = 0;
    }
  }
  if (lane == 0) wsum[wave] = cos_acc;
  __syncthreads();
  if (tid == 0) atomicAdd(aux_sum, wsum[0] + wsum[1] + wsum[2] + wsum[3]);
}

// ---------------------------------------------------------------------------
// recon[b,:] = dec_b + dec1_b + dec2_b + sum_slots a*decT[e] + c*(win?dec1T:dec2T)[e]
// ---------------------------------------------------------------------------
__global__ __launch_bounds__(256) void recon_kernel(
    const float* __restrict__ decT0, const float* __restrict__ decT1, const float* __restrict__ decT2,
    const float* __restrict__ db0, const float* __restrict__ db1, const float* __restrict__ db2,
    const int* __restrict__ topk_idx, const float* __restrict__ topk_val,
    const float* __restrict__ child_c, const int* __restrict__ win_flag,
    float* __restrict__ out) {
  int b = blockIdx.x;
  int tid = threadIdx.x;
  __shared__ int es[K_N];
  __shared__ float as[K_N], cs[K_N];
  __shared__ int wf[K_N];
  if (tid < K_N) {
    es[tid] = topk_idx[b * K_N + tid];
    as[tid] = topk_val[b * K_N + tid];
    cs[tid] = child_c[b * K_N + tid];
    wf[tid] = win_flag[b * K_N + tid];
  }
  __syncthreads();

  float acc0 = db0[tid] + db1[tid] + db2[tid];
  float acc1 = db0[tid + 256] + db1[tid + 256] + db2[tid + 256];
  float acc2 = db0[tid + 512] + db1[tid + 512] + db2[tid + 512];

  for (int s = 0; s < K_N; ++s) {
    float a = as[s];
    float c = cs[s];
    if (a == 0.f && c == 0.f) continue;
    int e = es[s];
    const float* col = decT0 + (size_t)e * M_N;
    acc0 = fmaf(a, col[tid], acc0);
    acc1 = fmaf(a, col[tid + 256], acc1);
    acc2 = fmaf(a, col[tid + 512], acc2);
    if (c != 0.f) {
      const float* ccol = (wf[s] ? decT1 : decT2) + (size_t)e * M_N;
      acc0 = fmaf(c, ccol[tid], acc0);
      acc1 = fmaf(c, ccol[tid + 256], acc1);
      acc2 = fmaf(c, ccol[tid + 512], acc2);
    }
  }
  out[(size_t)b * M_N + tid] = acc0;
  out[(size_t)b * M_N + tid + 256] = acc1;
  out[(size_t)b * M_N + tid + 512] = acc2;
}

// ---------------------------------------------------------------------------
// Final counts + aux scalar.
// ---------------------------------------------------------------------------
__global__ void finalize_kernel(const int* __restrict__ live_p, const int* __restrict__ live_c1,
                                const int* __restrict__ live_c2, const float* __restrict__ aux_sum,
                                float* __restrict__ out_tail) {
  int tid = threadIdx.x;
  int c0 = 0, c1 = 0, c2 = 0;
  for (int i = tid; i < E_N; i += 256) {
    c0 += live_p[i];
    c1 += live_c1[i];
    c2 += live_c2[i];
  }
  __shared__ int r0[256], r1[256], r2[256];
  r0[tid] = c0; r1[tid] = c1; r2[tid] = c2;
  __syncthreads();
  for (int s = 128; s > 0; s >>= 1) {
    if (tid < s) { r0[tid] += r0[tid + s]; r1[tid] += r1[tid + s]; r2[tid] += r2[tid + s]; }
    __syncthreads();
  }
  if (tid == 0) {
    out_tail[0] = (float)r0[0];
    out_tail[1] = (float)r1[0];
    out_tail[2] = (float)r2[0];
    out_tail[3] = -aux_sum[0] / (float)B_N;
  }
}

// ---------------------------------------------------------------------------
extern "C" void kernel_launch(void* const* d_in, const int* in_sizes, int n_in,
                              void* d_out, int out_size, void* d_ws, size_t ws_size,
                              hipStream_t stream) {
  const float* x     = (const float*)d_in[0];
  const float* enc_w = (const float*)d_in[1];
  const float* enc_b = (const float*)d_in[2];
  const float* dec_w = (const float*)d_in[3];
  const float* dec_b = (const float*)d_in[4];
  const float* e1w   = (const float*)d_in[5];
  const float* e1b   = (const float*)d_in[6];
  const float* d1w   = (const float*)d_in[7];
  const float* d1b   = (const float*)d_in[8];
  const float* e2w   = (const float*)d_in[9];
  const float* e2b   = (const float*)d_in[10];
  const float* d2w   = (const float*)d_in[11];
  const float* d2b   = (const float*)d_in[12];

  float* wsf = (float*)d_ws;
  size_t off = 0;
  float* pre = wsf + off;          off += (size_t)B_N * E_N;      // 33.5M
  float* decT0 = wsf + off;        off += (size_t)E_N * M_N;      // 12.6M
  float* decT1 = wsf + off;        off += (size_t)E_N * M_N;
  float* decT2 = wsf + off;        off += (size_t)E_N * M_N;
  float* stats = wsf + off;        off += 5 * (size_t)E_N;
  int*   tidx = (int*)(wsf + off); off += (size_t)B_N * K_N;
  float* tval = wsf + off;         off += (size_t)B_N * K_N;
  float* cc   = wsf + off;         off += (size_t)B_N * K_N;
  int*   wfl  = (int*)(wsf + off); off += (size_t)B_N * K_N;
  int*   livep  = (int*)(wsf + off); off += E_N;
  int*   livec1 = (int*)(wsf + off); off += E_N;
  int*   livec2 = (int*)(wsf + off); off += E_N;
  float* auxs = wsf + off;         off += 1;

  // zero live flags + aux accumulator (contiguous region)
  hipMemsetAsync(livep, 0, (3 * (size_t)E_N + 1) * sizeof(float), stream);

  colstats_kernel<<<E_N / 256, 256, 0, stream>>>(dec_w, d1w, d2w, stats);

  dim3 tgrid(E_N / 32, M_N / 32);
  dim3 tblk(32, 8);
  transpose_kernel<<<tgrid, tblk, 0, stream>>>(dec_w, decT0);
  transpose_kernel<<<tgrid, tblk, 0, stream>>>(d1w, decT1);
  transpose_kernel<<<tgrid, tblk, 0, stream>>>(d2w, decT2);

  gemm_pre_kernel<<<dim3(E_N / GBN, B_N / GBM), 256, 0, stream>>>(x, enc_w, enc_b, pre);

  topk_kernel<<<B_N, 256, 0, stream>>>(pre, tidx, tval, livep);

  child_kernel<<<B_N, 256, 0, stream>>>(x, e1w, e1b, e2w, e2b, tidx, tval, cc, wfl,
                                        livec1, livec2, stats, auxs);

  float* out = (float*)d_out;
  recon_kernel<<<B_N, 256, 0, stream>>>(decT0, decT1, decT2, dec_b, d1b, d2b,
                                        tidx, tval, cc, wfl, out);

  finalize_kernel<<<1, 256, 0, stream>>>(livep, livec1, livec2, auxs,
                                         out + (size_t)B_N * M_N);
}

// Round 3
// 841.899 us; speedup vs baseline: 1.4771x; 1.4771x over previous
//
#include <hip/hip_runtime.h>
#include <cstdint>
#include <cstddef>

#define B_N 2048
#define M_N 768
#define E_N 16384
#define K_N 32
#define EPSF 1e-8f

typedef __attribute__((ext_vector_type(8))) short short8;
typedef __attribute__((ext_vector_type(4))) float floatx4;
typedef __attribute__((ext_vector_type(4))) unsigned short ushort4v;

__device__ inline unsigned short f2bf(float f) {
  unsigned int u = __float_as_uint(f);
  unsigned int r = (u + 0x7fffu + ((u >> 16) & 1u)) >> 16;
  return (unsigned short)r;
}
__device__ inline float bf2f(unsigned short h) {
  return __uint_as_float(((unsigned int)h) << 16);
}

// ---------------------------------------------------------------------------
// Split f32 -> (hi, lo) bf16 pair.  n4 = n/4.
// ---------------------------------------------------------------------------
__global__ __launch_bounds__(256) void split_kernel(const float* __restrict__ in,
                                                    unsigned short* __restrict__ hi,
                                                    unsigned short* __restrict__ lo,
                                                    int n4) {
  int i = blockIdx.x * 256 + threadIdx.x;
  if (i >= n4) return;
  float4 v = ((const float4*)in)[i];
  ushort4v h, l;
  h.x = f2bf(v.x); l.x = f2bf(v.x - bf2f(h.x));
  h.y = f2bf(v.y); l.y = f2bf(v.y - bf2f(h.y));
  h.z = f2bf(v.z); l.z = f2bf(v.z - bf2f(h.z));
  h.w = f2bf(v.w); l.w = f2bf(v.w - bf2f(h.w));
  ((ushort4v*)hi)[i] = h;
  ((ushort4v*)lo)[i] = l;
}

// ---------------------------------------------------------------------------
// Column stats of the three decoders: np2, n1, n2, dp1, dp2  (each length E)
// ---------------------------------------------------------------------------
__global__ void colstats_kernel(const float* __restrict__ dw, const float* __restrict__ d1,
                                const float* __restrict__ d2, float* __restrict__ out5) {
  int e = blockIdx.x * 256 + threadIdx.x;
  float s0 = 0.f, s1 = 0.f, s2 = 0.f, s3 = 0.f, s4 = 0.f;
  for (int m = 0; m < M_N; ++m) {
    float a  = dw[(size_t)m * E_N + e];
    float b1 = d1[(size_t)m * E_N + e];
    float b2 = d2[(size_t)m * E_N + e];
    s0 = fmaf(a, a, s0);
    s1 = fmaf(b1, b1, s1);
    s2 = fmaf(b2, b2, s2);
    s3 = fmaf(a, b1, s3);
    s4 = fmaf(a, b2, s4);
  }
  out5[e] = s0;
  out5[E_N + e] = s1;
  out5[2 * E_N + e] = s2;
  out5[3 * E_N + e] = s3;
  out5[4 * E_N + e] = s4;
}

// ---------------------------------------------------------------------------
// Transpose [M_N, E_N] -> [E_N, M_N]
// ---------------------------------------------------------------------------
__global__ void transpose_kernel(const float* __restrict__ in, float* __restrict__ out) {
  __shared__ float tile[32][33];
  int tx = threadIdx.x;
  int ty = threadIdx.y;
  int e = blockIdx.x * 32 + tx;
  for (int r = 0; r < 32; r += 8) {
    int m = blockIdx.y * 32 + ty + r;
    tile[ty + r][tx] = in[(size_t)m * E_N + e];
  }
  __syncthreads();
  int m2 = blockIdx.y * 32 + tx;
  for (int r = 0; r < 32; r += 8) {
    int e2 = blockIdx.x * 32 + ty + r;
    out[(size_t)e2 * M_N + m2] = tile[tx][ty + r];
  }
}

// ---------------------------------------------------------------------------
// pre = x @ enc_w.T + enc_b  via split-bf16 MFMA (hi*hi + hi*lo + lo*hi).
// 128x128 tile, BK=32, 256 threads (4 waves), 4x4 16x16x32 MFMAs per wave.
// ---------------------------------------------------------------------------
#define TM 128
#define TN 128
#define TK 32
#define LDK 40  // LDS row stride (bf16 elems); 80 B keeps 16B alignment, 2-way banks

__global__ __launch_bounds__(256) void gemm_mfma_kernel(
    const unsigned short* __restrict__ Ahi, const unsigned short* __restrict__ Alo,
    const unsigned short* __restrict__ Bhi, const unsigned short* __restrict__ Blo,
    const float* __restrict__ bias, float* __restrict__ C) {
  __shared__ __align__(16) unsigned short As_hi[TM * LDK];
  __shared__ __align__(16) unsigned short As_lo[TM * LDK];
  __shared__ __align__(16) unsigned short Bs_hi[TM * LDK];
  __shared__ __align__(16) unsigned short Bs_lo[TM * LDK];

  int tid = threadIdx.x;
  int lane = tid & 63;
  int wave = tid >> 6;
  int i0 = blockIdx.y * TM;
  int j0 = blockIdx.x * TN;
  int wm = (wave >> 1) * 64;
  int wn = (wave & 1) * 64;

  int row0 = tid >> 2, c40 = tid & 3;
  int row1 = 64 + (tid >> 2), c41 = tid & 3;
  const unsigned short* pAhi0 = Ahi + (size_t)(i0 + row0) * M_N + c40 * 8;
  const unsigned short* pAhi1 = Ahi + (size_t)(i0 + row1) * M_N + c41 * 8;
  const unsigned short* pAlo0 = Alo + (size_t)(i0 + row0) * M_N + c40 * 8;
  const unsigned short* pAlo1 = Alo + (size_t)(i0 + row1) * M_N + c41 * 8;
  const unsigned short* pBhi0 = Bhi + (size_t)(j0 + row0) * M_N + c40 * 8;
  const unsigned short* pBhi1 = Bhi + (size_t)(j0 + row1) * M_N + c41 * 8;
  const unsigned short* pBlo0 = Blo + (size_t)(j0 + row0) * M_N + c40 * 8;
  const unsigned short* pBlo1 = Blo + (size_t)(j0 + row1) * M_N + c41 * 8;
  int l0 = row0 * LDK + c40 * 8;
  int l1 = row1 * LDK + c41 * 8;

  floatx4 acc[4][4];
#pragma unroll
  for (int i = 0; i < 4; ++i)
#pragma unroll
    for (int j = 0; j < 4; ++j) acc[i][j] = (floatx4){0.f, 0.f, 0.f, 0.f};

  int fr = lane & 15;
  int fk = (lane >> 4) * 8;

  short8 vAh0 = *(const short8*)pAhi0;
  short8 vAh1 = *(const short8*)pAhi1;
  short8 vAl0 = *(const short8*)pAlo0;
  short8 vAl1 = *(const short8*)pAlo1;
  short8 vBh0 = *(const short8*)pBhi0;
  short8 vBh1 = *(const short8*)pBhi1;
  short8 vBl0 = *(const short8*)pBlo0;
  short8 vBl1 = *(const short8*)pBlo1;

  for (int k0 = 0; k0 < M_N; k0 += TK) {
    __syncthreads();
    *(short8*)&As_hi[l0] = vAh0;
    *(short8*)&As_hi[l1] = vAh1;
    *(short8*)&As_lo[l0] = vAl0;
    *(short8*)&As_lo[l1] = vAl1;
    *(short8*)&Bs_hi[l0] = vBh0;
    *(short8*)&Bs_hi[l1] = vBh1;
    *(short8*)&Bs_lo[l0] = vBl0;
    *(short8*)&Bs_lo[l1] = vBl1;
    __syncthreads();

    if (k0 + TK < M_N) {
      int d = k0 + TK;
      vAh0 = *(const short8*)(pAhi0 + d);
      vAh1 = *(const short8*)(pAhi1 + d);
      vAl0 = *(const short8*)(pAlo0 + d);
      vAl1 = *(const short8*)(pAlo1 + d);
      vBh0 = *(const short8*)(pBhi0 + d);
      vBh1 = *(const short8*)(pBhi1 + d);
      vBl0 = *(const short8*)(pBlo0 + d);
      vBl1 = *(const short8*)(pBlo1 + d);
    }

    short8 ah[4], al[4], bh[4], bl[4];
#pragma unroll
    for (int t = 0; t < 4; ++t) {
      int ar = (wm + t * 16 + fr) * LDK + fk;
      int br = (wn + t * 16 + fr) * LDK + fk;
      ah[t] = *(const short8*)&As_hi[ar];
      al[t] = *(const short8*)&As_lo[ar];
      bh[t] = *(const short8*)&Bs_hi[br];
      bl[t] = *(const short8*)&Bs_lo[br];
    }
#pragma unroll
    for (int mi = 0; mi < 4; ++mi)
#pragma unroll
      for (int ni = 0; ni < 4; ++ni) {
        acc[mi][ni] = __builtin_amdgcn_mfma_f32_16x16x32_bf16(ah[mi], bh[ni], acc[mi][ni], 0, 0, 0);
        acc[mi][ni] = __builtin_amdgcn_mfma_f32_16x16x32_bf16(ah[mi], bl[ni], acc[mi][ni], 0, 0, 0);
        acc[mi][ni] = __builtin_amdgcn_mfma_f32_16x16x32_bf16(al[mi], bh[ni], acc[mi][ni], 0, 0, 0);
      }
  }

#pragma unroll
  for (int mi = 0; mi < 4; ++mi) {
    int rbase = i0 + wm + mi * 16 + (lane >> 4) * 4;
#pragma unroll
    for (int ni = 0; ni < 4; ++ni) {
      int col = j0 + wn + ni * 16 + (lane & 15);
      float bb = bias[col];
#pragma unroll
      for (int r = 0; r < 4; ++r) {
        C[(size_t)(rbase + r) * E_N + col] = acc[mi][ni][r] + bb;
      }
    }
  }
}

// ---------------------------------------------------------------------------
// Top-K per row via per-thread cached max + winner rescan. Destroys `pre`.
// ---------------------------------------------------------------------------
__global__ __launch_bounds__(256) void topk_kernel(float* __restrict__ pre,
                                                   int* __restrict__ topk_idx,
                                                   float* __restrict__ topk_val,
                                                   int* __restrict__ live_p) {
  int b = blockIdx.x;
  int tid = threadIdx.x;
  float* row = pre + (size_t)b * E_N;

  __shared__ float rv[256];
  __shared__ int ri[256];
  __shared__ float wv_s;
  __shared__ int wi_s, wt_s;

  float best = -INFINITY;
  int bidx = 0x7fffffff;
  for (int j = 0; j < E_N / 256; ++j) {
    int i = tid + j * 256;
    float v = row[i];
    if (v > best) { best = v; bidx = i; }
  }
  rv[tid] = best;
  ri[tid] = bidx;
  __syncthreads();

  for (int iter = 0; iter < K_N; ++iter) {
    if (tid < 64) {
      float v = rv[tid];
      int idx = ri[tid];
      int owner = tid;
#pragma unroll
      for (int s = 64; s < 256; s += 64) {
        float v2 = rv[tid + s];
        int i2 = ri[tid + s];
        if (v2 > v || (v2 == v && i2 < idx)) { v = v2; idx = i2; owner = tid + s; }
      }
#pragma unroll
      for (int off = 32; off > 0; off >>= 1) {
        float v2 = __shfl_down(v, off);
        int i2 = __shfl_down(idx, off);
        int o2 = __shfl_down(owner, off);
        if (v2 > v || (v2 == v && i2 < idx)) { v = v2; idx = i2; owner = o2; }
      }
      if (tid == 0) { wv_s = v; wi_s = idx; wt_s = owner; }
    }
    __syncthreads();
    int widx = wi_s;
    int wtid = wt_s;
    if (tid == 0) {
      topk_idx[b * K_N + iter] = widx;
      topk_val[b * K_N + iter] = wv_s;
      live_p[widx] = 1;
    }
    if (tid == wtid) {
      row[widx] = -INFINITY;
      float nb = -INFINITY;
      int nbi = 0x7fffffff;
      for (int j = 0; j < E_N / 256; ++j) {
        int i = tid + j * 256;
        float v2 = row[i];
        if (v2 > nb) { nb = v2; nbi = i; }
      }
      rv[tid] = nb;
      ri[tid] = nbi;
    }
    __syncthreads();
  }
}

// ---------------------------------------------------------------------------
// Per-active-slot children: pre1/pre2 dots, winner, c value, liveness, aux.
// ---------------------------------------------------------------------------
__global__ __launch_bounds__(256) void child_kernel(
    const float* __restrict__ x, const float* __restrict__ e1w, const float* __restrict__ e1b,
    const float* __restrict__ e2w, const float* __restrict__ e2b,
    const int* __restrict__ topk_idx, const float* __restrict__ topk_val,
    float* __restrict__ child_c, int* __restrict__ win_flag,
    int* __restrict__ live_c1, int* __restrict__ live_c2,
    const float* __restrict__ stats, float* __restrict__ aux_sum) {
  int b = blockIdx.x;
  int tid = threadIdx.x;
  int lane = tid & 63;
  int wave = tid >> 6;

  __shared__ float xs[M_N];
  __shared__ float wsum[4];
  for (int i = tid; i < M_N; i += 256) xs[i] = x[(size_t)b * M_N + i];
  __syncthreads();

  float cos_acc = 0.f;
  for (int s = wave; s < K_N; s += 4) {
    int e = topk_idx[b * K_N + s];
    float a = topk_val[b * K_N + s];
    if (a != 0.f) {
      float d1 = 0.f, d2 = 0.f;
#pragma unroll
      for (int j = 0; j < 3; ++j) {
        int m = (lane << 2) + j * 256;
        float4 xv = *(const float4*)&xs[m];
        float4 w1 = *(const float4*)&e1w[(size_t)e * M_N + m];
        float4 w2 = *(const float4*)&e2w[(size_t)e * M_N + m];
        d1 += xv.x * w1.x + xv.y * w1.y + xv.z * w1.z + xv.w * w1.w;
        d2 += xv.x * w2.x + xv.y * w2.y + xv.z * w2.z + xv.w * w2.w;
      }
#pragma unroll
      for (int off = 32; off > 0; off >>= 1) {
        d1 += __shfl_down(d1, off);
        d2 += __shfl_down(d2, off);
      }
      if (lane == 0) {
        float m1 = d1 + e1b[e];
        float m2 = d2 + e2b[e];
        bool win = m1 > m2;
        float f1 = win ? m1 : 0.f;
        float f2 = win ? 0.f : m2;
        float c = win ? f1 : f2;
        child_c[b * K_N + s] = c;
        win_flag[b * K_N + s] = win ? 1 : 0;
        if (f1 != 0.f) live_c1[e] = 1;
        if (f2 != 0.f) live_c2[e] = 1;
        if (a > 0.f) {
          float np2e = stats[e];
          float nce = win ? stats[E_N + e] : stats[2 * E_N + e];
          float dpc = win ? stats[3 * E_N + e] : stats[4 * E_N + e];
          float a2 = a * a;
          float dot = a2 * np2e + a * c * dpc;
          float normp = fabsf(a) * sqrtf(np2e);
          float comb2 = a2 * np2e + 2.f * a * c * dpc + c * c * nce;
          float normc = sqrtf(fmaxf(comb2, 0.f));
          cos_acc += dot / (fmaxf(normp, EPSF) * fmaxf(normc, EPSF));
        }
      }
    } else if (lane == 0) {
      child_c[b * K_N + s] = 0.f;
      win_flag[b * K_N + s] = 0;
    }
  }
  if (lane == 0) wsum[wave] = cos_acc;
  __syncthreads();
  if (tid == 0) atomicAdd(aux_sum, wsum[0] + wsum[1] + wsum[2] + wsum[3]);
}

// ---------------------------------------------------------------------------
// recon
// ---------------------------------------------------------------------------
__global__ __launch_bounds__(256) void recon_kernel(
    const float* __restrict__ decT0, const float* __restrict__ decT1, const float* __restrict__ decT2,
    const float* __restrict__ db0, const float* __restrict__ db1, const float* __restrict__ db2,
    const int* __restrict__ topk_idx, const float* __restrict__ topk_val,
    const float* __restrict__ child_c, const int* __restrict__ win_flag,
    float* __restrict__ out) {
  int b = blockIdx.x;
  int tid = threadIdx.x;
  __shared__ int es[K_N];
  __shared__ float as[K_N], cs[K_N];
  __shared__ int wf[K_N];
  if (tid < K_N) {
    es[tid] = topk_idx[b * K_N + tid];
    as[tid] = topk_val[b * K_N + tid];
    cs[tid] = child_c[b * K_N + tid];
    wf[tid] = win_flag[b * K_N + tid];
  }
  __syncthreads();

  float acc0 = db0[tid] + db1[tid] + db2[tid];
  float acc1 = db0[tid + 256] + db1[tid + 256] + db2[tid + 256];
  float acc2 = db0[tid + 512] + db1[tid + 512] + db2[tid + 512];

  for (int s = 0; s < K_N; ++s) {
    float a = as[s];
    float c = cs[s];
    if (a == 0.f && c == 0.f) continue;
    int e = es[s];
    const float* col = decT0 + (size_t)e * M_N;
    acc0 = fmaf(a, col[tid], acc0);
    acc1 = fmaf(a, col[tid + 256], acc1);
    acc2 = fmaf(a, col[tid + 512], acc2);
    if (c != 0.f) {
      const float* ccol = (wf[s] ? decT1 : decT2) + (size_t)e * M_N;
      acc0 = fmaf(c, ccol[tid], acc0);
      acc1 = fmaf(c, ccol[tid + 256], acc1);
      acc2 = fmaf(c, ccol[tid + 512], acc2);
    }
  }
  out[(size_t)b * M_N + tid] = acc0;
  out[(size_t)b * M_N + tid + 256] = acc1;
  out[(size_t)b * M_N + tid + 512] = acc2;
}

// ---------------------------------------------------------------------------
__global__ void finalize_kernel(const int* __restrict__ live_p, const int* __restrict__ live_c1,
                                const int* __restrict__ live_c2, const float* __restrict__ aux_sum,
                                float* __restrict__ out_tail) {
  int tid = threadIdx.x;
  int c0 = 0, c1 = 0, c2 = 0;
  for (int i = tid; i < E_N; i += 256) {
    c0 += live_p[i];
    c1 += live_c1[i];
    c2 += live_c2[i];
  }
  __shared__ int r0[256], r1[256], r2[256];
  r0[tid] = c0; r1[tid] = c1; r2[tid] = c2;
  __syncthreads();
  for (int s = 128; s > 0; s >>= 1) {
    if (tid < s) { r0[tid] += r0[tid + s]; r1[tid] += r1[tid + s]; r2[tid] += r2[tid + s]; }
    __syncthreads();
  }
  if (tid == 0) {
    out_tail[0] = (float)r0[0];
    out_tail[1] = (float)r1[0];
    out_tail[2] = (float)r2[0];
    out_tail[3] = -aux_sum[0] / (float)B_N;
  }
}

// ---------------------------------------------------------------------------
// Workspace layout (all offsets multiples of 64 floats = 256 B):
//   Big region (reused across phases):
//     phase 1 (split/gemm/topk): [pre 33.5M][xhi/xlo 1.57M][ewhi/ewlo 12.6M]
//     phase 2 (transpose/recon): [decT0 12.6M][decT1][decT2]   (overlaps phase-1)
//   Tail (persistent): stats, tidx, tval, cc, wfl, live block, auxs.
// Total ~192.5 MB (< proven-safe 286 MB).
// ---------------------------------------------------------------------------
extern "C" void kernel_launch(void* const* d_in, const int* in_sizes, int n_in,
                              void* d_out, int out_size, void* d_ws, size_t ws_size,
                              hipStream_t stream) {
  const float* x     = (const float*)d_in[0];
  const float* enc_w = (const float*)d_in[1];
  const float* enc_b = (const float*)d_in[2];
  const float* dec_w = (const float*)d_in[3];
  const float* dec_b = (const float*)d_in[4];
  const float* e1w   = (const float*)d_in[5];
  const float* e1b   = (const float*)d_in[6];
  const float* d1w   = (const float*)d_in[7];
  const float* d1b   = (const float*)d_in[8];
  const float* e2w   = (const float*)d_in[9];
  const float* e2b   = (const float*)d_in[10];
  const float* d2w   = (const float*)d_in[11];
  const float* d2b   = (const float*)d_in[12];

  float* wsf = (float*)d_ws;

  const size_t PRE_F  = (size_t)B_N * E_N;        // 33,554,432
  const size_t XSP_F  = (size_t)B_N * M_N / 2;    // 786,432 (hi or lo as floats)
  const size_t ESP_F  = (size_t)E_N * M_N / 2;    // 6,291,456
  const size_t DEC_F  = (size_t)E_N * M_N;        // 12,582,912
  const size_t BIG_F  = PRE_F + 2 * XSP_F + 2 * ESP_F;  // 47,710,208 floats

  // phase-1 aliases
  float* pre = wsf;
  unsigned short* xhi  = (unsigned short*)(wsf + PRE_F);
  unsigned short* xlo  = (unsigned short*)(wsf + PRE_F + XSP_F);
  unsigned short* ewhi = (unsigned short*)(wsf + PRE_F + 2 * XSP_F);
  unsigned short* ewlo = (unsigned short*)(wsf + PRE_F + 2 * XSP_F + ESP_F);
  // phase-2 aliases (overlap pre/splits; both dead by then)
  float* decT0 = wsf;
  float* decT1 = wsf + DEC_F;
  float* decT2 = wsf + 2 * DEC_F;

  size_t off = BIG_F;
  float* stats = wsf + off;           off += 5 * (size_t)E_N + 64;       // pad to keep mult-64
  off &= ~(size_t)63;
  int*   tidx = (int*)(wsf + off);    off += (size_t)B_N * K_N;
  float* tval = wsf + off;            off += (size_t)B_N * K_N;
  float* cc   = wsf + off;            off += (size_t)B_N * K_N;
  int*   wfl  = (int*)(wsf + off);    off += (size_t)B_N * K_N;
  int*   livep  = (int*)(wsf + off);  // contiguous: livep, livec1, livec2, auxs
  int*   livec1 = livep + E_N;
  int*   livec2 = livep + 2 * E_N;
  float* auxs   = (float*)(livep + 3 * E_N);

  hipMemsetAsync(livep, 0, (3 * (size_t)E_N + 1) * sizeof(float), stream);

  // phase 1: split -> gemm -> topk
  split_kernel<<<(B_N * M_N / 4 + 255) / 256, 256, 0, stream>>>(x, xhi, xlo, B_N * M_N / 4);
  split_kernel<<<(E_N * M_N / 4 + 255) / 256, 256, 0, stream>>>(enc_w, ewhi, ewlo, E_N * M_N / 4);

  gemm_mfma_kernel<<<dim3(E_N / TN, B_N / TM), 256, 0, stream>>>(xhi, xlo, ewhi, ewlo, enc_b, pre);

  topk_kernel<<<B_N, 256, 0, stream>>>(pre, tidx, tval, livep);

  // phase 2: decoder prep (reuses big region), then child/recon/finalize
  colstats_kernel<<<E_N / 256, 256, 0, stream>>>(dec_w, d1w, d2w, stats);

  dim3 tgrid(E_N / 32, M_N / 32);
  dim3 tblk(32, 8);
  transpose_kernel<<<tgrid, tblk, 0, stream>>>(dec_w, decT0);
  transpose_kernel<<<tgrid, tblk, 0, stream>>>(d1w, decT1);
  transpose_kernel<<<tgrid, tblk, 0, stream>>>(d2w, decT2);

  child_kernel<<<B_N, 256, 0, stream>>>(x, e1w, e1b, e2w, e2b, tidx, tval, cc, wfl,
                                        livec1, livec2, stats, auxs);

  float* out = (float*)d_out;
  recon_kernel<<<B_N, 256, 0, stream>>>(decT0, decT1, decT2, dec_b, d1b, d2b,
                                        tidx, tval, cc, wfl, out);

  finalize_kernel<<<1, 256, 0, stream>>>(livep, livec1, livec2, auxs,
                                         out + (size_t)B_N * M_N);
}

// Round 4
// 734.974 us; speedup vs baseline: 1.6920x; 1.1455x over previous
//
#include <hip/hip_runtime.h>
#include <cstdint>
#include <cstddef>

#define B_N 2048
#define M_N 768
#define E_N 16384
#define K_N 32
#define EPSF 1e-8f

typedef __attribute__((ext_vector_type(8))) short short8;
typedef __attribute__((ext_vector_type(4))) float floatx4;
typedef __attribute__((ext_vector_type(4))) unsigned short ushort4v;

__device__ inline unsigned short f2bf(float f) {
  unsigned int u = __float_as_uint(f);
  unsigned int r = (u + 0x7fffu + ((u >> 16) & 1u)) >> 16;
  return (unsigned short)r;
}
__device__ inline float bf2f(unsigned short h) {
  return __uint_as_float(((unsigned int)h) << 16);
}

// ---------------------------------------------------------------------------
// Split f32 -> (hi, lo) bf16 pair.  n4 = n/4.
// ---------------------------------------------------------------------------
__global__ __launch_bounds__(256) void split_kernel(const float* __restrict__ in,
                                                    unsigned short* __restrict__ hi,
                                                    unsigned short* __restrict__ lo,
                                                    int n4) {
  int i = blockIdx.x * 256 + threadIdx.x;
  if (i >= n4) return;
  float4 v = ((const float4*)in)[i];
  ushort4v h, l;
  h.x = f2bf(v.x); l.x = f2bf(v.x - bf2f(h.x));
  h.y = f2bf(v.y); l.y = f2bf(v.y - bf2f(h.y));
  h.z = f2bf(v.z); l.z = f2bf(v.z - bf2f(h.z));
  h.w = f2bf(v.w); l.w = f2bf(v.w - bf2f(h.w));
  ((ushort4v*)hi)[i] = h;
  ((ushort4v*)lo)[i] = l;
}

// ---------------------------------------------------------------------------
// Fused decoder prep: transpose all three [M,E]->[E,M] AND accumulate the
// 5 per-column stats (np2,n1,n2,dp1,dp2) from the same LDS tiles.
// stats must be pre-zeroed. grid (E/32, M/32), block (32,8).
// ---------------------------------------------------------------------------
__global__ void prep_dec_kernel(const float* __restrict__ dw, const float* __restrict__ d1,
                                const float* __restrict__ d2,
                                float* __restrict__ dT0, float* __restrict__ dT1,
                                float* __restrict__ dT2, float* __restrict__ stats) {
  __shared__ float t0[32][33], t1[32][33], t2[32][33];
  __shared__ float ps[5][8][32];
  int tx = threadIdx.x;  // 32 -> e within tile
  int ty = threadIdx.y;  // 8
  int e = blockIdx.x * 32 + tx;
  float s0 = 0.f, s1 = 0.f, s2 = 0.f, s3 = 0.f, s4 = 0.f;
  for (int r = 0; r < 32; r += 8) {
    int m = blockIdx.y * 32 + ty + r;
    float a  = dw[(size_t)m * E_N + e];
    float b1 = d1[(size_t)m * E_N + e];
    float b2 = d2[(size_t)m * E_N + e];
    t0[ty + r][tx] = a;
    t1[ty + r][tx] = b1;
    t2[ty + r][tx] = b2;
    s0 = fmaf(a, a, s0);
    s1 = fmaf(b1, b1, s1);
    s2 = fmaf(b2, b2, s2);
    s3 = fmaf(a, b1, s3);
    s4 = fmaf(a, b2, s4);
  }
  ps[0][ty][tx] = s0; ps[1][ty][tx] = s1; ps[2][ty][tx] = s2;
  ps[3][ty][tx] = s3; ps[4][ty][tx] = s4;
  __syncthreads();
  int m2 = blockIdx.y * 32 + tx;
  for (int r = 0; r < 32; r += 8) {
    int e2 = blockIdx.x * 32 + ty + r;
    dT0[(size_t)e2 * M_N + m2] = t0[tx][ty + r];
    dT1[(size_t)e2 * M_N + m2] = t1[tx][ty + r];
    dT2[(size_t)e2 * M_N + m2] = t2[tx][ty + r];
  }
  if (ty == 0) {
    float a0 = 0.f, a1 = 0.f, a2 = 0.f, a3 = 0.f, a4 = 0.f;
#pragma unroll
    for (int q = 0; q < 8; ++q) {
      a0 += ps[0][q][tx]; a1 += ps[1][q][tx]; a2 += ps[2][q][tx];
      a3 += ps[3][q][tx]; a4 += ps[4][q][tx];
    }
    atomicAdd(&stats[e], a0);
    atomicAdd(&stats[E_N + e], a1);
    atomicAdd(&stats[2 * E_N + e], a2);
    atomicAdd(&stats[3 * E_N + e], a3);
    atomicAdd(&stats[4 * E_N + e], a4);
  }
}

// ---------------------------------------------------------------------------
// pre = x @ enc_w.T + enc_b  via split-bf16 MFMA (hi*hi + hi*lo + lo*hi).
// ---------------------------------------------------------------------------
#define TM 128
#define TN 128
#define TK 32
#define LDK 40

__global__ __launch_bounds__(256) void gemm_mfma_kernel(
    const unsigned short* __restrict__ Ahi, const unsigned short* __restrict__ Alo,
    const unsigned short* __restrict__ Bhi, const unsigned short* __restrict__ Blo,
    const float* __restrict__ bias, float* __restrict__ C) {
  __shared__ __align__(16) unsigned short As_hi[TM * LDK];
  __shared__ __align__(16) unsigned short As_lo[TM * LDK];
  __shared__ __align__(16) unsigned short Bs_hi[TM * LDK];
  __shared__ __align__(16) unsigned short Bs_lo[TM * LDK];

  int tid = threadIdx.x;
  int lane = tid & 63;
  int wave = tid >> 6;
  int i0 = blockIdx.y * TM;
  int j0 = blockIdx.x * TN;
  int wm = (wave >> 1) * 64;
  int wn = (wave & 1) * 64;

  int row0 = tid >> 2, c40 = tid & 3;
  int row1 = 64 + (tid >> 2), c41 = tid & 3;
  const unsigned short* pAhi0 = Ahi + (size_t)(i0 + row0) * M_N + c40 * 8;
  const unsigned short* pAhi1 = Ahi + (size_t)(i0 + row1) * M_N + c41 * 8;
  const unsigned short* pAlo0 = Alo + (size_t)(i0 + row0) * M_N + c40 * 8;
  const unsigned short* pAlo1 = Alo + (size_t)(i0 + row1) * M_N + c41 * 8;
  const unsigned short* pBhi0 = Bhi + (size_t)(j0 + row0) * M_N + c40 * 8;
  const unsigned short* pBhi1 = Bhi + (size_t)(j0 + row1) * M_N + c41 * 8;
  const unsigned short* pBlo0 = Blo + (size_t)(j0 + row0) * M_N + c40 * 8;
  const unsigned short* pBlo1 = Blo + (size_t)(j0 + row1) * M_N + c41 * 8;
  int l0 = row0 * LDK + c40 * 8;
  int l1 = row1 * LDK + c41 * 8;

  floatx4 acc[4][4];
#pragma unroll
  for (int i = 0; i < 4; ++i)
#pragma unroll
    for (int j = 0; j < 4; ++j) acc[i][j] = (floatx4){0.f, 0.f, 0.f, 0.f};

  int fr = lane & 15;
  int fk = (lane >> 4) * 8;

  short8 vAh0 = *(const short8*)pAhi0;
  short8 vAh1 = *(const short8*)pAhi1;
  short8 vAl0 = *(const short8*)pAlo0;
  short8 vAl1 = *(const short8*)pAlo1;
  short8 vBh0 = *(const short8*)pBhi0;
  short8 vBh1 = *(const short8*)pBhi1;
  short8 vBl0 = *(const short8*)pBlo0;
  short8 vBl1 = *(const short8*)pBlo1;

  for (int k0 = 0; k0 < M_N; k0 += TK) {
    __syncthreads();
    *(short8*)&As_hi[l0] = vAh0;
    *(short8*)&As_hi[l1] = vAh1;
    *(short8*)&As_lo[l0] = vAl0;
    *(short8*)&As_lo[l1] = vAl1;
    *(short8*)&Bs_hi[l0] = vBh0;
    *(short8*)&Bs_hi[l1] = vBh1;
    *(short8*)&Bs_lo[l0] = vBl0;
    *(short8*)&Bs_lo[l1] = vBl1;
    __syncthreads();

    if (k0 + TK < M_N) {
      int d = k0 + TK;
      vAh0 = *(const short8*)(pAhi0 + d);
      vAh1 = *(const short8*)(pAhi1 + d);
      vAl0 = *(const short8*)(pAlo0 + d);
      vAl1 = *(const short8*)(pAlo1 + d);
      vBh0 = *(const short8*)(pBhi0 + d);
      vBh1 = *(const short8*)(pBhi1 + d);
      vBl0 = *(const short8*)(pBlo0 + d);
      vBl1 = *(const short8*)(pBlo1 + d);
    }

    short8 ah[4], al[4], bh[4], bl[4];
#pragma unroll
    for (int t = 0; t < 4; ++t) {
      int ar = (wm + t * 16 + fr) * LDK + fk;
      int br = (wn + t * 16 + fr) * LDK + fk;
      ah[t] = *(const short8*)&As_hi[ar];
      al[t] = *(const short8*)&As_lo[ar];
      bh[t] = *(const short8*)&Bs_hi[br];
      bl[t] = *(const short8*)&Bs_lo[br];
    }
#pragma unroll
    for (int mi = 0; mi < 4; ++mi)
#pragma unroll
      for (int ni = 0; ni < 4; ++ni) {
        acc[mi][ni] = __builtin_amdgcn_mfma_f32_16x16x32_bf16(ah[mi], bh[ni], acc[mi][ni], 0, 0, 0);
        acc[mi][ni] = __builtin_amdgcn_mfma_f32_16x16x32_bf16(ah[mi], bl[ni], acc[mi][ni], 0, 0, 0);
        acc[mi][ni] = __builtin_amdgcn_mfma_f32_16x16x32_bf16(al[mi], bh[ni], acc[mi][ni], 0, 0, 0);
      }
  }

#pragma unroll
  for (int mi = 0; mi < 4; ++mi) {
    int rbase = i0 + wm + mi * 16 + (lane >> 4) * 4;
#pragma unroll
    for (int ni = 0; ni < 4; ++ni) {
      int col = j0 + wn + ni * 16 + (lane & 15);
      float bb = bias[col];
#pragma unroll
      for (int r = 0; r < 4; ++r) {
        C[(size_t)(rbase + r) * E_N + col] = acc[mi][ni][r] + bb;
      }
    }
  }
}

// ---------------------------------------------------------------------------
// Exact top-K per row via radix-select on the monotone u32 key.
// Matches jax.lax.top_k (ties -> lowest index). No serial rescans.
// ---------------------------------------------------------------------------
__global__ __launch_bounds__(256) void topk_kernel(const float* __restrict__ pre,
                                                   int* __restrict__ topk_idx,
                                                   float* __restrict__ topk_val,
                                                   int* __restrict__ live_p) {
  int b = blockIdx.x;
  int tid = threadIdx.x;
  const float* row = pre + (size_t)b * E_N;

  __shared__ unsigned int hist[2048];
  __shared__ float candV[2048];
  __shared__ int candI[2048];
  __shared__ float defV[K_N];
  __shared__ int defI[K_N];
  __shared__ int s_T, s_nDef, s_nCand;

  for (int i = tid; i < 2048; i += 256) hist[i] = 0;
  if (tid == 0) { s_nDef = 0; s_nCand = 0; }
  __syncthreads();

  // pass 1: histogram of top-11 key bits
  for (int j = 0; j < E_N / 256; ++j) {
    int i = tid + j * 256;
    unsigned int u = __float_as_uint(row[i]);
    unsigned int key = (u & 0x80000000u) ? ~u : (u | 0x80000000u);
    atomicAdd(&hist[key >> 21], 1u);
  }
  __syncthreads();

  if (tid == 0) {
    unsigned int cum = 0;
    for (int bk = 2047; bk >= 0; --bk) {
      cum += hist[bk];
      if (cum >= K_N) { s_T = bk; break; }
    }
  }
  __syncthreads();
  int T = s_T;

  // pass 2: collect definite (bucket > T) and candidates (bucket == T)
  for (int j = 0; j < E_N / 256; ++j) {
    int i = tid + j * 256;
    float v = row[i];
    unsigned int u = __float_as_uint(v);
    unsigned int key = (u & 0x80000000u) ? ~u : (u | 0x80000000u);
    int bk = key >> 21;
    if (bk > T) {
      int d = atomicAdd(&s_nDef, 1);
      defV[d] = v;
      defI[d] = i;
    } else if (bk == T) {
      int c = atomicAdd(&s_nCand, 1);
      candV[c] = v;
      candI[c] = i;
    }
  }
  __syncthreads();
  int nDef = s_nDef;        // < K_N by construction
  int nCand = s_nCand;
  int need = K_N - nDef;

  if (tid < nDef) {
    topk_idx[b * K_N + tid] = defI[tid];
    topk_val[b * K_N + tid] = defV[tid];
    live_p[defI[tid]] = 1;
  }
  // rank candidates by (value desc, index asc); rank < need -> selected
  for (int c = tid; c < nCand; c += 256) {
    float v = candV[c];
    int idx = candI[c];
    int r = 0;
    for (int j2 = 0; j2 < nCand; ++j2) {
      float vj = candV[j2];
      r += (vj > v) || (vj == v && candI[j2] < idx);
    }
    if (r < need) {
      int slot = nDef + r;
      topk_idx[b * K_N + slot] = idx;
      topk_val[b * K_N + slot] = v;
      live_p[idx] = 1;
    }
  }
}

// ---------------------------------------------------------------------------
// Fused child + recon per row b.
// Phase 1: per-slot child dots (e1w/e2w gathers), winner, c, liveness, aux.
// Phase 2: recon accumulation from decT gathers.
// ---------------------------------------------------------------------------
__global__ __launch_bounds__(256) void child_recon_kernel(
    const float* __restrict__ x, const float* __restrict__ e1w, const float* __restrict__ e1b,
    const float* __restrict__ e2w, const float* __restrict__ e2b,
    const int* __restrict__ topk_idx, const float* __restrict__ topk_val,
    int* __restrict__ live_c1, int* __restrict__ live_c2,
    const float* __restrict__ stats, float* __restrict__ aux_sum,
    const float* __restrict__ decT0, const float* __restrict__ decT1,
    const float* __restrict__ decT2,
    const float* __restrict__ db0, const float* __restrict__ db1,
    const float* __restrict__ db2, float* __restrict__ out) {
  int b = blockIdx.x;
  int tid = threadIdx.x;
  int lane = tid & 63;
  int wave = tid >> 6;

  __shared__ float xs[M_N];
  __shared__ int es[K_N];
  __shared__ float as[K_N], cs[K_N];
  __shared__ int wf[K_N];
  __shared__ float wsum[4];

  if (tid < K_N) {
    es[tid] = topk_idx[b * K_N + tid];
    as[tid] = topk_val[b * K_N + tid];
  }
  for (int i = tid; i < M_N; i += 256) xs[i] = x[(size_t)b * M_N + i];
  __syncthreads();

  float cos_acc = 0.f;
  for (int s = wave; s < K_N; s += 4) {
    int e = es[s];
    float a = as[s];
    if (a != 0.f) {
      float d1 = 0.f, d2 = 0.f;
#pragma unroll
      for (int j = 0; j < 3; ++j) {
        int m = (lane << 2) + j * 256;
        float4 xv = *(const float4*)&xs[m];
        float4 w1 = *(const float4*)&e1w[(size_t)e * M_N + m];
        float4 w2 = *(const float4*)&e2w[(size_t)e * M_N + m];
        d1 += xv.x * w1.x + xv.y * w1.y + xv.z * w1.z + xv.w * w1.w;
        d2 += xv.x * w2.x + xv.y * w2.y + xv.z * w2.z + xv.w * w2.w;
      }
#pragma unroll
      for (int off = 32; off > 0; off >>= 1) {
        d1 += __shfl_down(d1, off);
        d2 += __shfl_down(d2, off);
      }
      if (lane == 0) {
        float m1 = d1 + e1b[e];
        float m2 = d2 + e2b[e];
        bool win = m1 > m2;
        float f1 = win ? m1 : 0.f;
        float f2 = win ? 0.f : m2;
        float c = win ? f1 : f2;
        cs[s] = c;
        wf[s] = win ? 1 : 0;
        if (f1 != 0.f) live_c1[e] = 1;
        if (f2 != 0.f) live_c2[e] = 1;
        if (a > 0.f) {
          float np2e = stats[e];
          float nce = win ? stats[E_N + e] : stats[2 * E_N + e];
          float dpc = win ? stats[3 * E_N + e] : stats[4 * E_N + e];
          float a2 = a * a;
          float dot = a2 * np2e + a * c * dpc;
          float normp = fabsf(a) * sqrtf(np2e);
          float comb2 = a2 * np2e + 2.f * a * c * dpc + c * c * nce;
          float normc = sqrtf(fmaxf(comb2, 0.f));
          cos_acc += dot / (fmaxf(normp, EPSF) * fmaxf(normc, EPSF));
        }
      }
    } else if (lane == 0) {
      cs[s] = 0.f;
      wf[s] = 0;
    }
  }
  if (lane == 0) wsum[wave] = cos_acc;
  __syncthreads();
  if (tid == 0) atomicAdd(aux_sum, wsum[0] + wsum[1] + wsum[2] + wsum[3]);

  // phase 2: recon
  float acc0 = db0[tid] + db1[tid] + db2[tid];
  float acc1 = db0[tid + 256] + db1[tid + 256] + db2[tid + 256];
  float acc2 = db0[tid + 512] + db1[tid + 512] + db2[tid + 512];

  for (int s = 0; s < K_N; ++s) {
    float a = as[s];
    float c = cs[s];
    if (a == 0.f && c == 0.f) continue;
    int e = es[s];
    const float* col = decT0 + (size_t)e * M_N;
    acc0 = fmaf(a, col[tid], acc0);
    acc1 = fmaf(a, col[tid + 256], acc1);
    acc2 = fmaf(a, col[tid + 512], acc2);
    if (c != 0.f) {
      const float* ccol = (wf[s] ? decT1 : decT2) + (size_t)e * M_N;
      acc0 = fmaf(c, ccol[tid], acc0);
      acc1 = fmaf(c, ccol[tid + 256], acc1);
      acc2 = fmaf(c, ccol[tid + 512], acc2);
    }
  }
  out[(size_t)b * M_N + tid] = acc0;
  out[(size_t)b * M_N + tid + 256] = acc1;
  out[(size_t)b * M_N + tid + 512] = acc2;
}

// ---------------------------------------------------------------------------
__global__ void finalize_kernel(const int* __restrict__ live_p, const int* __restrict__ live_c1,
                                const int* __restrict__ live_c2, const float* __restrict__ aux_sum,
                                float* __restrict__ out_tail) {
  int tid = threadIdx.x;
  int c0 = 0, c1 = 0, c2 = 0;
  for (int i = tid; i < E_N; i += 256) {
    c0 += live_p[i];
    c1 += live_c1[i];
    c2 += live_c2[i];
  }
  __shared__ int r0[256], r1[256], r2[256];
  r0[tid] = c0; r1[tid] = c1; r2[tid] = c2;
  __syncthreads();
  for (int s = 128; s > 0; s >>= 1) {
    if (tid < s) { r0[tid] += r0[tid + s]; r1[tid] += r1[tid + s]; r2[tid] += r2[tid + s]; }
    __syncthreads();
  }
  if (tid == 0) {
    out_tail[0] = (float)r0[0];
    out_tail[1] = (float)r1[0];
    out_tail[2] = (float)r2[0];
    out_tail[3] = -aux_sum[0] / (float)B_N;
  }
}

// ---------------------------------------------------------------------------
// Workspace (all offsets multiples of 64 floats):
//   Big region (reused): phase 1 [pre | xhi xlo | ewhi ewlo], phase 2 [decT0..2]
//   Tail: [stats 5E | livep E | livec1 E | livec2 E | aux 1]  (zeroed once)
//         [tidx | tval]
// ---------------------------------------------------------------------------
extern "C" void kernel_launch(void* const* d_in, const int* in_sizes, int n_in,
                              void* d_out, int out_size, void* d_ws, size_t ws_size,
                              hipStream_t stream) {
  const float* x     = (const float*)d_in[0];
  const float* enc_w = (const float*)d_in[1];
  const float* enc_b = (const float*)d_in[2];
  const float* dec_w = (const float*)d_in[3];
  const float* dec_b = (const float*)d_in[4];
  const float* e1w   = (const float*)d_in[5];
  const float* e1b   = (const float*)d_in[6];
  const float* d1w   = (const float*)d_in[7];
  const float* d1b   = (const float*)d_in[8];
  const float* e2w   = (const float*)d_in[9];
  const float* e2b   = (const float*)d_in[10];
  const float* d2w   = (const float*)d_in[11];
  const float* d2b   = (const float*)d_in[12];

  float* wsf = (float*)d_ws;

  const size_t PRE_F = (size_t)B_N * E_N;
  const size_t XSP_F = (size_t)B_N * M_N / 2;
  const size_t ESP_F = (size_t)E_N * M_N / 2;
  const size_t DEC_F = (size_t)E_N * M_N;
  const size_t BIG_F = PRE_F + 2 * XSP_F + 2 * ESP_F;

  float* pre = wsf;
  unsigned short* xhi  = (unsigned short*)(wsf + PRE_F);
  unsigned short* xlo  = (unsigned short*)(wsf + PRE_F + XSP_F);
  unsigned short* ewhi = (unsigned short*)(wsf + PRE_F + 2 * XSP_F);
  unsigned short* ewlo = (unsigned short*)(wsf + PRE_F + 2 * XSP_F + ESP_F);
  float* decT0 = wsf;
  float* decT1 = wsf + DEC_F;
  float* decT2 = wsf + 2 * DEC_F;

  size_t off = BIG_F;
  float* stats  = wsf + off;
  int*   livep  = (int*)(wsf + off + 5 * (size_t)E_N);
  int*   livec1 = livep + E_N;
  int*   livec2 = livep + 2 * E_N;
  float* auxs   = (float*)(livep + 3 * E_N);
  off += 8 * (size_t)E_N + 64;
  off &= ~(size_t)63;
  int*   tidx = (int*)(wsf + off);    off += (size_t)B_N * K_N;
  float* tval = wsf + off;            off += (size_t)B_N * K_N;

  // zero stats + live flags + aux in one shot
  hipMemsetAsync(stats, 0, (8 * (size_t)E_N + 1) * sizeof(float), stream);

  // phase 1: split -> gemm -> topk
  split_kernel<<<(B_N * M_N / 4 + 255) / 256, 256, 0, stream>>>(x, xhi, xlo, B_N * M_N / 4);
  split_kernel<<<(E_N * M_N / 4 + 255) / 256, 256, 0, stream>>>(enc_w, ewhi, ewlo, E_N * M_N / 4);

  gemm_mfma_kernel<<<dim3(E_N / TN, B_N / TM), 256, 0, stream>>>(xhi, xlo, ewhi, ewlo, enc_b, pre);

  topk_kernel<<<B_N, 256, 0, stream>>>(pre, tidx, tval, livep);

  // phase 2: fused decoder prep (overwrites big region), then fused child+recon
  prep_dec_kernel<<<dim3(E_N / 32, M_N / 32), dim3(32, 8), 0, stream>>>(
      dec_w, d1w, d2w, decT0, decT1, decT2, stats);

  float* out = (float*)d_out;
  child_recon_kernel<<<B_N, 256, 0, stream>>>(x, e1w, e1b, e2w, e2b, tidx, tval,
                                              livec1, livec2, stats, auxs,
                                              decT0, decT1, decT2, dec_b, d1b, d2b, out);

  finalize_kernel<<<1, 256, 0, stream>>>(livep, livec1, livec2, auxs,
                                         out + (size_t)B_N * M_N);
}